// Round 1
// baseline (482.495 us; speedup 1.0000x reference)
//
#include <hip/hip_runtime.h>
#include <hip/hip_bf16.h>
#include <math.h>

#define CIN   2048
#define CMID  1024
#define NB    32
#define HWSP  196
#define NPOS  6272      // 32*196
#define WELEM 2097152   // CMID*CIN

typedef __attribute__((ext_vector_type(4))) float f32x4;
typedef __attribute__((ext_vector_type(8))) short short8;

typedef const __attribute__((address_space(1))) unsigned int* as1_u32p;
typedef __attribute__((address_space(3))) unsigned int* as3_u32p;

__device__ __forceinline__ void gload_lds16(const void* g, void* l) {
  __builtin_amdgcn_global_load_lds((as1_u32p)g, (as3_u32p)l, 16, 0, 0);
}

// ---------------- pack weights: w1 -> Wpack[9][1024][2048] bf16, BN fold, head-weight transpose
__global__ __launch_bounds__(256) void pack_w(
    const float* __restrict__ w1, const float* __restrict__ b1,
    const float* __restrict__ g1, const float* __restrict__ be1,
    const float* __restrict__ mu1, const float* __restrict__ va1,
    const float* __restrict__ wsel, const float* __restrict__ wbox,
    __hip_bfloat16* __restrict__ Wp, float* __restrict__ inv1,
    float* __restrict__ add1, float* __restrict__ Wh)
{
  const int gid = blockIdx.x * 256 + threadIdx.x;
  if (gid < WELEM) {
    const float* src = w1 + (long)gid * 9;
    float v[9];
    #pragma unroll
    for (int k = 0; k < 9; ++k) v[k] = src[k];
    #pragma unroll
    for (int k = 0; k < 9; ++k)
      Wp[(long)k * WELEM + gid] = __float2bfloat16(v[k]);
  }
  if (gid < CMID) {
    float iv = g1[gid] / sqrtf(va1[gid] + 1e-5f);
    inv1[gid] = iv;
    add1[gid] = b1[gid] * iv + be1[gid] - mu1[gid] * iv;
  }
  if (gid < CMID * 54) {
    int co = gid / 54, o = gid % 54;
    Wh[gid] = (o < 18) ? wsel[o * CMID + co] : wbox[(o - 18) * CMID + co];
  }
}

// ---------------- pack x: NCHW fp32 -> Xpad[32][16][16][2048] bf16 (zero border)
__global__ __launch_bounds__(256) void pack_x(
    const float* __restrict__ x, __hip_bfloat16* __restrict__ Xp)
{
  __shared__ __hip_bfloat16 lx[64 * HWSP];
  const int n = blockIdx.x;      // 0..31
  const int cc = blockIdx.y;     // 0..31
  const int ci0 = cc * 64;
  const float* src = x + ((long)n * CIN + ci0) * HWSP;
  for (int i = threadIdx.x; i < 64 * HWSP; i += 256)
    lx[i] = __float2bfloat16(src[i]);
  __syncthreads();
  const int ci = threadIdx.x & 63;
  const int pq = threadIdx.x >> 6;   // 0..3
  __hip_bfloat16* dst = Xp + (long)n * 256 * CIN + ci0 + ci;
  const __hip_bfloat16 z = __float2bfloat16(0.f);
  #pragma unroll
  for (int k = 0; k < 64; ++k) {
    int pos = k * 4 + pq;
    int y = pos >> 4, xx = pos & 15;
    __hip_bfloat16 v = z;
    if (y >= 1 && y <= 14 && xx >= 1 && xx <= 14)
      v = lx[ci * HWSP + (y - 1) * 14 + (xx - 1)];
    dst[(long)pos * CIN] = v;
  }
}

// ---------------- conv 3x3 as 9 shifted GEMMs: C[1024][6272] = sum_kk A_kk[1024][2048] * B_kk[2048][6272]
// m97-style: 128x128 tile, BK=32, 4 waves x (4x4) 16x16x32 bf16 MFMA, global_load_lds staging.
__global__ __launch_bounds__(256) void conv_mfma(
    const __hip_bfloat16* __restrict__ Wp,
    const __hip_bfloat16* __restrict__ Xp,
    const float* __restrict__ inv1,
    const float* __restrict__ add1,
    float* __restrict__ hout)
{
  __shared__ __hip_bfloat16 As[128 * 32];
  __shared__ __hip_bfloat16 Bs[128 * 32];

  const int t = threadIdx.x;
  const int mtile = blockIdx.x;   // 0..7
  const int ntile = blockIdx.y;   // 0..48
  const int lane = t & 63;
  const int wv = t >> 6;
  const int wr = wv >> 1, wc = wv & 1;

  // staging: thread t covers rows (t>>2) and 64+(t>>2), cols (t&3)*8
  const int srow = t >> 2;
  const int scol = (t & 3) * 8;

  const long arow0 = (long)(mtile * 128 + srow) * CIN + scol;

  const int jj0 = ntile * 128 + srow;
  const int jj1 = jj0 + 64;
  const int n0 = jj0 / HWSP, p0 = jj0 % HWSP;
  const int h0 = p0 / 14, w0 = p0 % 14;
  const int n1 = jj1 / HWSP, p1 = jj1 % HWSP;
  const int h1 = p1 / 14, w1_ = p1 % 14;

  f32x4 acc[4][4] = {};

  for (int kk = 0; kk < 9; ++kk) {
    const int kh = kk / 3, kw = kk % 3;
    const long abase = (long)kk * WELEM + arow0;
    const long bbase0 = ((long)(n0 * 256 + (h0 + kh) * 16 + (w0 + kw))) * CIN + scol;
    const long bbase1 = ((long)(n1 * 256 + (h1 + kh) * 16 + (w1_ + kw))) * CIN + scol;
    for (int ck = 0; ck < CIN; ck += 32) {
      __syncthreads();
      gload_lds16(Wp + abase + ck,             (char*)As + t * 16);
      gload_lds16(Wp + abase + 64 * CIN + ck,  (char*)As + 4096 + t * 16);
      gload_lds16(Xp + bbase0 + ck,            (char*)Bs + t * 16);
      gload_lds16(Xp + bbase1 + ck,            (char*)Bs + 4096 + t * 16);
      __syncthreads();
      const int fr = lane & 15;
      const int ks = (lane >> 4) * 8;
      short8 a[4], b[4];
      #pragma unroll
      for (int i = 0; i < 4; ++i)
        a[i] = *(const short8*)((const char*)As + ((wr * 64 + i * 16 + fr) * 32 + ks) * 2);
      #pragma unroll
      for (int i = 0; i < 4; ++i)
        b[i] = *(const short8*)((const char*)Bs + ((wc * 64 + i * 16 + fr) * 32 + ks) * 2);
      #pragma unroll
      for (int m = 0; m < 4; ++m)
        #pragma unroll
        for (int n = 0; n < 4; ++n)
          acc[m][n] = __builtin_amdgcn_mfma_f32_16x16x32_bf16(a[m], b[n], acc[m][n], 0, 0, 0);
    }
  }

  // epilogue: fused bias+BN+ReLU, write h[co][j]
  const int fr = lane & 15;
  const int rg = (lane >> 4) * 4;
  #pragma unroll
  for (int m = 0; m < 4; ++m) {
    const int co0 = mtile * 128 + wr * 64 + m * 16 + rg;
    #pragma unroll
    for (int r = 0; r < 4; ++r) {
      const int co = co0 + r;
      const float iv = inv1[co];
      const float ad = add1[co];
      #pragma unroll
      for (int n = 0; n < 4; ++n) {
        const int j = ntile * 128 + wc * 64 + n * 16 + fr;
        float v = acc[m][n][r] * iv + ad;
        hout[(long)co * NPOS + j] = v > 0.f ? v : 0.f;
      }
    }
  }
}

// ---------------- fused 1x1 heads + softmax/BN/reshape epilogue
__global__ __launch_bounds__(256) void head_fused(
    const float* __restrict__ h, const float* __restrict__ Wh,
    const float* __restrict__ bsel, const float* __restrict__ bbox,
    const float* __restrict__ gb, const float* __restrict__ beb,
    const float* __restrict__ mub, const float* __restrict__ vab,
    float* __restrict__ out)
{
  __shared__ float red[4 * 64 * 54];
  const int t = threadIdx.x;
  const int jl = t & 63;
  const int cg = __builtin_amdgcn_readfirstlane(t >> 6);  // 0..3, wave-uniform
  const int j0 = blockIdx.x * 64;
  const int j = j0 + jl;

  float acc[54];
  #pragma unroll
  for (int o = 0; o < 54; ++o) acc[o] = 0.f;

  const float* hp = h + (long)(cg * 256) * NPOS + j;
  const float* wp = Wh + cg * 256 * 54;
  for (int i = 0; i < 256; ++i) {
    float hv = hp[(long)i * NPOS];
    const float* wr_ = wp + i * 54;
    #pragma unroll
    for (int o = 0; o < 54; ++o) acc[o] += hv * wr_[o];
  }
  #pragma unroll
  for (int o = 0; o < 54; ++o) red[(cg * 64 + jl) * 54 + o] = acc[o];
  __syncthreads();

  // scores: 64 j x 9 pairs -> relu -> softmax over pair
  for (int idx = t; idx < 576; idx += 256) {
    int jj = idx / 9, pr = idx % 9;
    float s0 = bsel[2 * pr], s1 = bsel[2 * pr + 1];
    #pragma unroll
    for (int c = 0; c < 4; ++c) {
      s0 += red[(c * 64 + jj) * 54 + 2 * pr];
      s1 += red[(c * 64 + jj) * 54 + 2 * pr + 1];
    }
    s0 = fmaxf(s0, 0.f); s1 = fmaxf(s1, 0.f);
    float mx = fmaxf(s0, s1);
    float e0 = expf(s0 - mx), e1 = expf(s1 - mx);
    float inv = 1.f / (e0 + e1);
    int jg = j0 + jj;
    int nn = jg / HWSP, p = jg % HWSP;
    long off = ((long)nn * 1764 + p * 9 + pr) * 2;
    out[off] = e0 * inv;
    out[off + 1] = e1 * inv;
  }

  // boxes: 64 j x 36 -> BN -> relu -> *419
  float* outb = out + (long)NB * 1764 * 2;
  for (int idx = t; idx < 2304; idx += 256) {
    int jj = idx / 36, o = idx % 36;
    float v = bbox[o];
    #pragma unroll
    for (int c = 0; c < 4; ++c) v += red[(c * 64 + jj) * 54 + 18 + o];
    float iv = gb[o] / sqrtf(vab[o] + 1e-5f);
    v = v * iv + (beb[o] - mub[o] * iv);
    v = fmaxf(v, 0.f) * 419.f;
    int jg = j0 + jj;
    int nn = jg / HWSP, p = jg % HWSP;
    outb[((long)nn * 1764 + p * 9 + (o >> 2)) * 4 + (o & 3)] = v;
  }
}

extern "C" void kernel_launch(void* const* d_in, const int* in_sizes, int n_in,
                              void* d_out, int out_size, void* d_ws, size_t ws_size,
                              hipStream_t stream) {
  const float* x    = (const float*)d_in[0];
  const float* w1   = (const float*)d_in[1];
  const float* b1   = (const float*)d_in[2];
  const float* g1   = (const float*)d_in[3];
  const float* be1  = (const float*)d_in[4];
  const float* mu1  = (const float*)d_in[5];
  const float* va1  = (const float*)d_in[6];
  const float* wsel = (const float*)d_in[7];
  const float* bsel = (const float*)d_in[8];
  const float* wbox = (const float*)d_in[9];
  const float* bbox = (const float*)d_in[10];
  const float* gb   = (const float*)d_in[11];
  const float* beb  = (const float*)d_in[12];
  const float* mub  = (const float*)d_in[13];
  const float* vab  = (const float*)d_in[14];

  char* ws = (char*)d_ws;
  __hip_bfloat16* Wp = (__hip_bfloat16*)(ws);                    // 9*1024*2048*2   = 37748736
  __hip_bfloat16* Xp = (__hip_bfloat16*)(ws + 37748736);         // 32*256*2048*2   = 33554432
  float* hbuf        = (float*)(ws + 71303168);                  // 1024*6272*4     = 25690112
  float* inv1        = (float*)(ws + 96993280);                  // 4096
  float* add1        = (float*)(ws + 96997376);                  // 4096
  float* Wh          = (float*)(ws + 97001472);                  // 1024*54*4       = 221184

  hipLaunchKernelGGL(pack_w, dim3(8192), dim3(256), 0, stream,
                     w1, b1, g1, be1, mu1, va1, wsel, wbox, Wp, inv1, add1, Wh);
  hipLaunchKernelGGL(pack_x, dim3(32, 32), dim3(256), 0, stream, x, Xp);
  hipLaunchKernelGGL(conv_mfma, dim3(8, 49), dim3(256), 0, stream,
                     Wp, Xp, inv1, add1, hbuf);
  hipLaunchKernelGGL(head_fused, dim3(98), dim3(256), 0, stream,
                     hbuf, Wh, bsel, bbox, gb, beb, mub, vab, (float*)d_out);
}